// Round 3
// baseline (155.693 us; speedup 1.0000x reference)
//
#include <hip/hip_runtime.h>
#include <hip/hip_bf16.h>

#define VOCAB 100000
#define DIM   128
#define BATCH 16384
#define KNEG  20

// Phase A: sequentially stream out_embed (51.2 MB) to populate the 256 MB
// memory-side Infinity Cache at streaming efficiency, so phase B's random
// row gathers fill L2 from L3 instead of random-access DRAM.
__global__ __launch_bounds__(256) void warm_kernel(
    const float4* __restrict__ p, int n4, float* __restrict__ ws)
{
    const int tid  = blockIdx.x * blockDim.x + threadIdx.x;
    const int step = gridDim.x * blockDim.x;
    float s = 0.0f;
    for (int i = tid; i < n4; i += step) {
        const float4 v = p[i];
        s += v.x + v.y + v.z + v.w;
    }
    // Wave-reduce and write one dummy float per wave into d_ws so the
    // loads can't be dead-code-eliminated. (ws re-poisoned each call; fine.)
    #pragma unroll
    for (int m = 1; m < 64; m <<= 1) s += __shfl_xor(s, m, 64);
    if ((threadIdx.x & 63) == 0) ws[(tid >> 6) & 4095] = s;
}

// Phase B: half-wave (32 lanes) per batch row; lane sub holds float4 =
// row[4*sub..4*sub+3]. Each 64-lane wave processes two rows; the xor
// butterfly with masks 1..16 stays within each 32-lane half.
__global__ __launch_bounds__(256) void skipgram_loss_kernel(
    const int*   __restrict__ target,
    const int*   __restrict__ context,
    const int*   __restrict__ neg_samples,
    const float* __restrict__ in_embed,
    const float* __restrict__ out_embed,
    float*       __restrict__ out)
{
    const int lane  = threadIdx.x & 63;
    const int half  = lane >> 5;
    const int sub   = lane & 31;
    const int wave  = threadIdx.x >> 6;
    const int wpb   = blockDim.x >> 6;
    const int gwave = blockIdx.x * wpb + wave;
    const int nwav  = gridDim.x * wpb;

    float acc = 0.0f;

    for (int b0 = gwave * 2; b0 < BATCH; b0 += nwav * 2) {
        const int b    = b0 + half;
        const int trow = target[b];
        const int crow = context[b];

        const float4 t4 = *(const float4*)(in_embed  + (size_t)trow * DIM + sub * 4);
        const float4 c4 = *(const float4*)(out_embed + (size_t)crow * DIM + sub * 4);

        const int myidx = (sub < KNEG) ? neg_samples[b * KNEG + sub] : 0;
        int nrow[KNEG];
        #pragma unroll
        for (int k = 0; k < KNEG; ++k)
            nrow[k] = __shfl(myidx, k, 32);

        float p[KNEG + 1];
        p[0] = t4.x * c4.x + t4.y * c4.y + t4.z * c4.z + t4.w * c4.w;

        #pragma unroll
        for (int k = 0; k < KNEG; ++k) {
            const float4 n4 = *(const float4*)(out_embed + (size_t)nrow[k] * DIM + sub * 4);
            p[k + 1] = t4.x * n4.x + t4.y * n4.y + t4.z * n4.z + t4.w * n4.w;
        }

        #pragma unroll
        for (int k = 0; k < KNEG + 1; ++k) {
            float v = p[k];
            #pragma unroll
            for (int m = 1; m < 32; m <<= 1)
                v += __shfl_xor(v, m, 64);
            const float x  = (k == 0) ? v : -v;
            const float ls = fminf(x, 0.0f) - __logf(1.0f + __expf(-fabsf(x)));
            acc += ls;
        }
    }

    __shared__ float smem[8];
    if (sub == 0) smem[wave * 2 + half] = acc;
    __syncthreads();
    if (threadIdx.x == 0) {
        float tot = 0.0f;
        for (int i = 0; i < wpb * 2; ++i) tot += smem[i];
        atomicAdd(out, -tot * (1.0f / (float)BATCH));
    }
}

extern "C" void kernel_launch(void* const* d_in, const int* in_sizes, int n_in,
                              void* d_out, int out_size, void* d_ws, size_t ws_size,
                              hipStream_t stream) {
    const int*   target      = (const int*)  d_in[0];
    const int*   context     = (const int*)  d_in[1];
    const int*   neg_samples = (const int*)  d_in[2];
    const float* in_embed    = (const float*)d_in[3];
    const float* out_embed   = (const float*)d_in[4];
    float*       out         = (float*)d_out;

    hipMemsetAsync(out, 0, sizeof(float), stream);

    // Phase A: warm L3 with out_embed (sequential stream, ~51.2 MB).
    const int n4 = VOCAB * DIM / 4;   // 3.2M float4
    warm_kernel<<<1024, 256, 0, stream>>>(
        (const float4*)out_embed, n4, (float*)d_ws);

    // Phase B: gathers now fill from L3. Stream order serializes A -> B.
    skipgram_loss_kernel<<<2048, 256, 0, stream>>>(
        target, context, neg_samples, in_embed, out_embed, out);
}